// Round 10
// baseline (911.025 us; speedup 1.0000x reference)
//
#include <hip/hip_runtime.h>
#include <hip/hip_fp16.h>
#include <hip/hip_cooperative_groups.h>

namespace cg = cooperative_groups;

// PolyConv: h = sum_k theta[k] * L_sym^k x,  L_sym = I - D^{-1/2} A D^{-1/2}
// N=100000 nodes, E=1600000 edges, F=64 features, 5 theta terms.
//
// Round 24: r23 build (binA multisplit + binB convert) unchanged; the 4
// gather passes fused into ONE persistent cooperative kernel (1024 blocks
// x 256 thr, co-resident), grid-stride over node pairs, threadfence +
// grid.sync() between passes. Removes 3 inter-pass launch+drain bubbles
// (~12-18us of GPU idle). Per-pair gather body identical to r21-r23.

constexpr int kF = 64;
constexpr int BSHIFT = 8;             // bucket = dst >> 8  (256 nodes/bucket)
constexpr int NB = 1 << BSHIFT;       // 256 nodes per bucket
constexpr int TILEA = 4096;           // edges per binA block (8/thread)
constexpr int KMAX = 512;             // array bound for K (=391)
constexpr int GBLK = 1024;            // cooperative gather grid (4 blk/CU)

typedef unsigned nv4u __attribute__((ext_vector_type(4)));   // nontemporal-safe
typedef float    nv4f __attribute__((ext_vector_type(4)));

static __device__ __forceinline__ float hlo(unsigned u) {        // low f16 -> f32
    return __half2float(__ushort_as_half((unsigned short)(u & 0xffffu)));
}
static __device__ __forceinline__ float hhi(unsigned u) {        // high f16 -> f32
    return __half2float(__ushort_as_half((unsigned short)(u >> 16)));
}
static __device__ __forceinline__ unsigned pack2h(float a, float b) { // RNE
    return (unsigned)__half_as_ushort(__float2half_rn(a)) |
           ((unsigned)__half_as_ushort(__float2half_rn(b)) << 16);
}
static __device__ __forceinline__ unsigned padd2(unsigned a, unsigned b) {
    __half2 ha = *reinterpret_cast<__half2*>(&a);
    __half2 hb = *reinterpret_cast<__half2*>(&b);
    __half2 hc = __hadd2(ha, hb);                 // v_pk_add_f16
    return *reinterpret_cast<unsigned*>(&hc);
}

// Phase A: pure edge multisplit into K buckets. Per 4096-edge tile: LDS
// histogram -> KMAX scan -> LDS counting-sort -> global reserve ->
// bucket-ordered coalesced write-out.
__global__ void k_binA(const int* __restrict__ src, const int* __restrict__ dst,
                       unsigned* __restrict__ pairs, int* __restrict__ gcursor,
                       int E, int K, int cap) {
    __shared__ unsigned stage[TILEA];        // 16 KB bucket-sorted entries
    __shared__ unsigned short stageB[TILEA]; // 8 KB bucket id per slot
    __shared__ int hist[KMAX];               // counts -> cursors
    __shared__ int lb[KMAX];                 // local exclusive base
    __shared__ int gb[KMAX];                 // global base per bucket
    const int tid = threadIdx.x;        // blockDim = 512
    const long long tb = (long long)blockIdx.x * TILEA;
    const int tcount = (int)min((long long)TILEA, (long long)E - tb);

    hist[tid] = 0;
    __syncthreads();
    int dc[8], sc[8];
    #pragma unroll
    for (int k = 0; k < 8; ++k) {
        int i = tid + k * 512;
        if (i < tcount) {
            dc[k] = dst[tb + i];
            sc[k] = src[tb + i];
            atomicAdd(&hist[dc[k] >> BSHIFT], 1);
        } else {
            dc[k] = -1;
        }
    }
    __syncthreads();
    const int cnt = hist[tid];
    lb[tid] = cnt;
    __syncthreads();
    for (int o = 1; o < KMAX; o <<= 1) {
        int t = (tid >= o) ? lb[tid - o] : 0;
        __syncthreads();
        lb[tid] += t;
        __syncthreads();
    }
    const int excl = lb[tid] - cnt;          // local exclusive base
    __syncthreads();
    lb[tid] = excl;
    gb[tid] = (tid < K && cnt > 0) ? atomicAdd(&gcursor[tid], cnt) : 0;
    hist[tid] = excl;                        // reuse as LDS scatter cursor
    __syncthreads();
    #pragma unroll
    for (int k = 0; k < 8; ++k) {
        if (dc[k] >= 0) {
            int d = dc[k];
            int b = d >> BSHIFT;
            int pos = atomicAdd(&hist[b], 1);
            stage[pos]  = ((unsigned)(d & (NB - 1)) << 23) | (unsigned)sc[k];
            stageB[pos] = (unsigned short)b;
        }
    }
    __syncthreads();
    // bucket-ordered write-out: consecutive j -> consecutive addresses
    for (int j = tid; j < tcount; j += 512) {
        int b = stageB[j];
        pairs[(size_t)b * cap + gb[b] + (j - lb[b])] = stage[j];
    }
}

// Phase B: one block (512 thr) per bucket of 256 nodes. In-kernel gbase
// scan, per-node counts -> LDS scan -> rp/dinv2/rdeg, scatter plain src
// ints to csr via absolute LDS cursors, write csr0 (first 8 slots per
// node, padded with N), then convert own bucket's x (fp32) -> xb (f16)
// AND g0 = f16(dinv * x). Zeroes g0's row N (OOB gather slots).
__global__ void k_binB(const unsigned* __restrict__ pairs, const int* __restrict__ gcursor,
                       int* __restrict__ rp, float* __restrict__ dinv2,
                       float* __restrict__ rdeg, int* __restrict__ csr,
                       int* __restrict__ csr0,
                       const float4* __restrict__ x4,
                       uint4* __restrict__ xb4, uint4* __restrict__ g0,
                       int N, int E, int K, int cap) {
    __shared__ int gsc[KMAX];
    __shared__ int cnt[NB];
    __shared__ int stmp[NB];
    __shared__ int cur[NB];
    __shared__ float sdinv[NB];
    const int b = blockIdx.x;
    const int tid = threadIdx.x;        // blockDim = 512

    if (b == 0 && tid < 8)               // zero row N of g0
        g0[((size_t)N << 3) + tid] = make_uint4(0, 0, 0, 0);

    int gv = (tid < K) ? gcursor[tid] : 0;
    gsc[tid] = gv;
    __syncthreads();
    for (int o = 1; o < KMAX; o <<= 1) {
        int t = (tid >= o) ? gsc[tid - o] : 0;
        __syncthreads();
        gsc[tid] += t;
        __syncthreads();
    }
    const int ecnt = gcursor[b];
    const int base = gsc[b] - ecnt;     // inclusive - own = exclusive
    const unsigned* bp = pairs + (size_t)b * cap;

    if (tid < NB) cnt[tid] = 0;
    __syncthreads();
    for (int i = tid; i < ecnt; i += 512)
        atomicAdd(&cnt[bp[i] >> 23], 1);
    __syncthreads();
    int v = (tid < NB) ? cnt[tid] : 0;
    if (tid < NB) stmp[tid] = v;
    __syncthreads();
    for (int o = 1; o < NB; o <<= 1) {
        int t = (tid >= o && tid < NB) ? stmp[tid - o] : 0;
        __syncthreads();
        if (tid < NB) stmp[tid] += t;
        __syncthreads();
    }
    int node = (b << BSHIFT) + tid;
    if (tid < NB) {
        int abs0 = base + stmp[tid] - v;            // exclusive, absolute
        cur[tid] = abs0;
        float d = fmaxf((float)v, 1.0f);
        sdinv[tid] = rsqrtf(d);
        if (node < N) {
            rp[node] = abs0;
            dinv2[node] = 1.0f / d;
            rdeg[node]  = sqrtf(d);
        }
    }
    if (b == K - 1 && tid == 0) rp[N] = E;
    __syncthreads();
    for (int i = tid; i < ecnt; i += 512) {
        unsigned p = bp[i];
        int pos = atomicAdd(&cur[p >> 23], 1);      // absolute csr index
        csr[pos] = (int)(p & 0x7FFFFFu);
    }
    __syncthreads();                                 // csr of this bucket done
    // csr0: first 8 slots per node, padded with N (zero row)
    if (tid < NB && node < N) {
        int abs0 = base + stmp[tid] - v;
        int4 q0, q1;
        q0.x = (0 < v) ? csr[abs0 + 0] : N;
        q0.y = (1 < v) ? csr[abs0 + 1] : N;
        q0.z = (2 < v) ? csr[abs0 + 2] : N;
        q0.w = (3 < v) ? csr[abs0 + 3] : N;
        q1.x = (4 < v) ? csr[abs0 + 4] : N;
        q1.y = (5 < v) ? csr[abs0 + 5] : N;
        q1.z = (6 < v) ? csr[abs0 + 6] : N;
        q1.w = (7 < v) ? csr[abs0 + 7] : N;
        *(int4*)(csr0 + ((size_t)node << 3))     = q0;
        *(int4*)(csr0 + ((size_t)node << 3) + 4) = q1;
    }
    // fused convert for this bucket's nodes: x (fp32) -> xb, g0 = dinv*x
    const int nbase = b << BSHIFT;
    const int qmax = min(NB, N - nbase) << 3;       // 8 uint4 per node
    uint4* g0p = g0 + ((size_t)nbase << 3);
    for (int q = tid; q < qmax; q += 512) {
        int gq = ((nbase + (q >> 3)) << 3) + (q & 7);   // global uint4 idx
        float4 a = x4[2 * gq];
        float4 bb = x4[2 * gq + 1];
        uint4 xo;
        xo.x = pack2h(a.x, a.y);
        xo.y = pack2h(a.z, a.w);
        xo.z = pack2h(bb.x, bb.y);
        xo.w = pack2h(bb.z, bb.w);
        xb4[gq] = xo;
        float di = sdinv[q >> 3];
        uint4 go;
        go.x = pack2h(di * a.x, di * a.y);
        go.y = pack2h(di * a.z, di * a.w);
        go.z = pack2h(di * bb.x, di * bb.y);
        go.w = pack2h(di * bb.z, di * bb.w);
        g0p[q] = go;
    }
}

// One node-pair gather (body identical to r21-r23 k_gather).
template <bool LAST>
static __device__ __forceinline__ void gather_pair(
        int wid, int lane,
        const int* __restrict__ rp, const int* __restrict__ csr,
        const int* __restrict__ csr0,
        const unsigned short* __restrict__ gin,
        const float* __restrict__ dinv2,
        unsigned short* __restrict__ gout,
        const unsigned short* __restrict__ xb,
        const unsigned short* __restrict__ g1t,
        const unsigned short* __restrict__ g2t,
        const float* __restrict__ rdeg,
        float* __restrict__ h, int n,
        float t0, float t1, float t2, float t3, float t4) {
    int half = lane >> 5;
    int r = (lane >> 3) & 3;
    int c = lane & 7;
    int node = wid * 2 + half;
    if (wid * 2 >= n) return;
    bool valid = node < n;

    // first-iteration row indices: independent of rp (breaks the chain)
    int s1 = n, s2 = n;
    if (valid) {
        s1 = csr0[((size_t)node << 3) + r];
        s2 = csr0[((size_t)node << 3) + r + 4];
    }
    int beg = valid ? rp[node] : 0;
    int end = valid ? rp[node + 1] : 0;

    // hoisted epilogue loads (node-addressed, exec-masked to 16 lanes)
    const bool ep = (r == 0) && valid;
    size_t off = ((size_t)node << 6) + (c << 3);
    uint4 rr = make_uint4(0, 0, 0, 0);
    float d2 = 0.f, rd = 0.f;
    nv4u xv = {0u, 0u, 0u, 0u}, aa = {0u, 0u, 0u, 0u}, bb = {0u, 0u, 0u, 0u};
    if (ep) {
        rr = *(const uint4*)(gin + off);
        d2 = dinv2[node];
        if (LAST) {
            xv = __builtin_nontemporal_load((const nv4u*)(xb + off));
            aa = __builtin_nontemporal_load((const nv4u*)(g1t + off));
            bb = __builtin_nontemporal_load((const nv4u*)(g2t + off));
            rd = rdeg[node];
        }
    }

    int len = end - beg;
    int olen = __shfl_xor(len, 32, 64);
    int mlen = (len > olen) ? len : olen;   // pair max -> uniform trip count

    unsigned acc[4] = {0u, 0u, 0u, 0u};     // packed f16 pairs

    // pipeline state: current rows (in flight), next row indices
    uint4 rc1 = *(const uint4*)(gin + ((size_t)s1 << 6) + (c << 3));
    uint4 rc2 = *(const uint4*)(gin + ((size_t)s2 << 6) + (c << 3));
    int sn1 = n, sn2 = n;
    {
        int j1b = beg + 8 + r, j2b = j1b + 4;
        bool vb = 8 < mlen;
        bool b1 = vb && (j1b < end), b2 = vb && (j2b < end);
        sn1 = csr[b1 ? j1b : 0]; sn1 = b1 ? sn1 : n;
        sn2 = csr[b2 ? j2b : 0]; sn2 = b2 ? sn2 : n;
    }
    for (int i = 0; i < mlen; i += 8) {
        // issue NEXT iteration's rows (independent of rc1/rc2 wait)
        uint4 rn1 = *(const uint4*)(gin + ((size_t)sn1 << 6) + (c << 3));
        uint4 rn2 = *(const uint4*)(gin + ((size_t)sn2 << 6) + (c << 3));
        // prefetch csr two iterations ahead
        int j1n = beg + i + 16 + r, j2n = j1n + 4;
        bool vn = (i + 16) < mlen;
        bool t1c = vn && (j1n < end), t2c = vn && (j2n < end);
        int st1 = csr[t1c ? j1n : 0]; st1 = t1c ? st1 : n;
        int st2 = csr[t2c ? j2n : 0]; st2 = t2c ? st2 : n;
        // accumulate CURRENT rows (packed f16)
        acc[0] = padd2(acc[0], rc1.x); acc[1] = padd2(acc[1], rc1.y);
        acc[2] = padd2(acc[2], rc1.z); acc[3] = padd2(acc[3], rc1.w);
        acc[0] = padd2(acc[0], rc2.x); acc[1] = padd2(acc[1], rc2.y);
        acc[2] = padd2(acc[2], rc2.z); acc[3] = padd2(acc[3], rc2.w);
        // rotate pipeline
        rc1 = rn1; rc2 = rn2;
        sn1 = st1; sn2 = st2;
    }
    #pragma unroll
    for (int m = 8; m <= 16; m <<= 1) {
        #pragma unroll
        for (int i = 0; i < 4; ++i)
            acc[i] = padd2(acc[i], __shfl_xor(acc[i], m, 64));
    }

    if (ep) {                                // lanes 0..7 and 32..39
        float v[8];
        v[0] = hlo(rr.x) - d2 * hlo(acc[0]); v[1] = hhi(rr.x) - d2 * hhi(acc[0]);
        v[2] = hlo(rr.y) - d2 * hlo(acc[1]); v[3] = hhi(rr.y) - d2 * hhi(acc[1]);
        v[4] = hlo(rr.z) - d2 * hlo(acc[2]); v[5] = hhi(rr.z) - d2 * hhi(acc[2]);
        v[6] = hlo(rr.w) - d2 * hlo(acc[3]); v[7] = hhi(rr.w) - d2 * hhi(acc[3]);
        if (!LAST) {
            nv4u o;
            o.x = pack2h(v[0], v[1]);
            o.y = pack2h(v[2], v[3]);
            o.z = pack2h(v[4], v[5]);
            o.w = pack2h(v[6], v[7]);
            __builtin_nontemporal_store(o, (nv4u*)(gout + off));
        } else {
            float s1f = rd * t1, s2f = rd * t2, s3f = rd * t3, s4f = rd * t4;
            nv4f h0, h1;
            h0.x = t0 * hlo(xv.x) + s1f * hlo(aa.x) + s2f * hlo(bb.x) + s3f * hlo(rr.x) + s4f * v[0];
            h0.y = t0 * hhi(xv.x) + s1f * hhi(aa.x) + s2f * hhi(bb.x) + s3f * hhi(rr.x) + s4f * v[1];
            h0.z = t0 * hlo(xv.y) + s1f * hlo(aa.y) + s2f * hlo(bb.y) + s3f * hlo(rr.y) + s4f * v[2];
            h0.w = t0 * hhi(xv.y) + s1f * hhi(aa.y) + s2f * hhi(bb.y) + s3f * hhi(rr.y) + s4f * v[3];
            h1.x = t0 * hlo(xv.z) + s1f * hlo(aa.z) + s2f * hlo(bb.z) + s3f * hlo(rr.z) + s4f * v[4];
            h1.y = t0 * hhi(xv.z) + s1f * hhi(aa.z) + s2f * hhi(bb.z) + s3f * hhi(rr.z) + s4f * v[5];
            h1.z = t0 * hlo(xv.w) + s1f * hlo(aa.w) + s2f * hlo(bb.w) + s3f * hlo(rr.w) + s4f * v[6];
            h1.w = t0 * hhi(xv.w) + s1f * hhi(aa.w) + s2f * hhi(bb.w) + s3f * hhi(rr.w) + s4f * v[7];
            __builtin_nontemporal_store(h0, (nv4f*)(h + off));
            __builtin_nontemporal_store(h1, (nv4f*)(h + off + 4));
        }
    }
}

// Persistent cooperative gather: all 4 passes, grid.sync() between.
__global__ void k_gather4(const int* __restrict__ rp, const int* __restrict__ csr,
                          const int* __restrict__ csr0,
                          unsigned short* __restrict__ g0,
                          unsigned short* __restrict__ g1,
                          unsigned short* __restrict__ g2,
                          unsigned short* __restrict__ g3,
                          const float* __restrict__ dinv2,
                          const unsigned short* __restrict__ xb,
                          const float* __restrict__ rdeg,
                          float* __restrict__ h, int n, int npairs,
                          float t0, float t1, float t2, float t3, float t4) {
    cg::grid_group grid = cg::this_grid();
    const int gwave  = (blockIdx.x * blockDim.x + threadIdx.x) >> 6;
    const int nwaves = (gridDim.x * blockDim.x) >> 6;
    const int lane   = threadIdx.x & 63;

    // zero row n of g1/g2/g3 (g0's row n written by binB)
    if (blockIdx.x == 0 && threadIdx.x < 24) {
        unsigned short* t = (threadIdx.x < 8) ? g1 : (threadIdx.x < 16) ? g2 : g3;
        *(((uint4*)(t + ((size_t)n << 6))) + (threadIdx.x & 7)) = make_uint4(0, 0, 0, 0);
    }

    for (int p = gwave; p < npairs; p += nwaves)
        gather_pair<false>(p, lane, rp, csr, csr0, g0, dinv2, g1,
                           nullptr, nullptr, nullptr, nullptr, nullptr,
                           n, 0, 0, 0, 0, 0);
    __threadfence();
    grid.sync();
    for (int p = gwave; p < npairs; p += nwaves)
        gather_pair<false>(p, lane, rp, csr, csr0, g1, dinv2, g2,
                           nullptr, nullptr, nullptr, nullptr, nullptr,
                           n, 0, 0, 0, 0, 0);
    __threadfence();
    grid.sync();
    for (int p = gwave; p < npairs; p += nwaves)
        gather_pair<false>(p, lane, rp, csr, csr0, g2, dinv2, g3,
                           nullptr, nullptr, nullptr, nullptr, nullptr,
                           n, 0, 0, 0, 0, 0);
    __threadfence();
    grid.sync();
    for (int p = gwave; p < npairs; p += nwaves)
        gather_pair<true>(p, lane, rp, csr, csr0, g3, dinv2, nullptr,
                          xb, g1, g2, rdeg, h, n, t0, t1, t2, t3, t4);
}

extern "C" void kernel_launch(void* const* d_in, const int* in_sizes, int n_in,
                              void* d_out, int out_size, void* d_ws, size_t ws_size,
                              hipStream_t stream) {
    const float* x  = (const float*)d_in[0];
    const int*   ei = (const int*)d_in[1];   // edge_index [2, E] row-major
    const int N = in_sizes[0] / kF;
    const int E = in_sizes[1] / 2;
    const int* src = ei;
    const int* dst = ei + E;
    float* h = (float*)d_out;

    const int K = (N + NB - 1) >> BSHIFT;         // 391 buckets (K <= KMAX)
    const int cap = 2 * ((E + K - 1) / K);        // per-bucket capacity

    // workspace (~76 MB): gcursor | rp | dinv2 | rdeg | csr | csr0 | xb |
    // g0 | g1 (aliases pairs; pairs dead after binB) | g2 | g3
    char* ws = (char*)d_ws;
    size_t off = 0;
    auto carve = [&](size_t bytes) {
        void* p = ws + off;
        off = (off + bytes + 511) & ~(size_t)511;
        return p;
    };
    size_t gbytes = (size_t)(N + 1) * kF * 2;
    int*            gcursor = (int*)carve((size_t)KMAX * 4);
    int*            rp      = (int*)carve((size_t)(N + 1) * 4);
    float*          dinv2   = (float*)carve((size_t)N * 4);
    float*          rdeg    = (float*)carve((size_t)N * 4);
    int*            csr     = (int*)carve((size_t)E * 4);
    int*            csr0    = (int*)carve((size_t)N * 8 * 4);
    unsigned short* xb      = (unsigned short*)carve((size_t)N * kF * 2);
    unsigned short* g0      = (unsigned short*)carve(gbytes);
    size_t pbytes = (size_t)K * cap * 4;
    unsigned short* g1      = (unsigned short*)carve(gbytes > pbytes ? gbytes : pbytes);
    unsigned short* g2      = (unsigned short*)carve(gbytes);
    unsigned short* g3      = (unsigned short*)carve(gbytes);
    unsigned*       pairs   = (unsigned*)g1;       // alias (dead after binB)

    const float theta[5] = {0.6f, -0.4f, 0.3f, -0.2f, 0.1f};

    // ---- CSR build (multisplit); binB also does x->xb and g0 ----
    hipMemsetAsync(gcursor, 0, (size_t)KMAX * 4, stream);
    k_binA<<<(E + TILEA - 1) / TILEA, 512, 0, stream>>>(src, dst, pairs, gcursor,
                                                        E, K, cap);
    k_binB<<<K, 512, 0, stream>>>(pairs, gcursor, rp, dinv2, rdeg, csr, csr0,
                                  (const float4*)x, (uint4*)xb, (uint4*)g0,
                                  N, E, K, cap);

    // ---- fused 4-pass gather (persistent cooperative) ----
    int npairs = (N + 1) / 2;
    float t0 = theta[0], t1 = theta[1], t2 = theta[2], t3 = theta[3], t4 = theta[4];
    void* args[] = {
        (void*)&rp, (void*)&csr, (void*)&csr0,
        (void*)&g0, (void*)&g1, (void*)&g2, (void*)&g3,
        (void*)&dinv2, (void*)&xb, (void*)&rdeg, (void*)&h,
        (void*)&N, (void*)&npairs,
        (void*)&t0, (void*)&t1, (void*)&t2, (void*)&t3, (void*)&t4
    };
    hipLaunchCooperativeKernel((void*)k_gather4, dim3(GBLK), dim3(256),
                               args, 0, stream);
}

// Round 11
// 234.459 us; speedup vs baseline: 3.8856x; 3.8856x over previous
//
#include <hip/hip_runtime.h>
#include <hip/hip_fp16.h>

// PolyConv: h = sum_k theta[k] * L_sym^k x,  L_sym = I - D^{-1/2} A D^{-1/2}
// N=100000 nodes, E=1600000 edges, F=64 features, 5 theta terms.
//
// Round 25: REVERT to r23 (237.3us session best). r24's persistent
// cooperative gather fused the 4 passes but dropped occupancy 75%->48%
// and serialized ~12 pairs per wave (802us: latency-bound, VALUBusy 8.6%).
// Structure: binA pure multisplit (LDS counting sort, bucket-ordered
// write-out) -> binB (per-bucket CSR + csr0 + x->xb/g0 f16 convert) ->
// 4 gather launches (csr0 prologue, f16 packed accumulate, hoisted
// epilogue; pass 4 fuses the h-combine).

constexpr int kF = 64;
constexpr int BSHIFT = 8;             // bucket = dst >> 8  (256 nodes/bucket)
constexpr int NB = 1 << BSHIFT;       // 256 nodes per bucket
constexpr int TILEA = 4096;           // edges per binA block (8/thread)
constexpr int KMAX = 512;             // array bound for K (=391)

typedef unsigned nv4u __attribute__((ext_vector_type(4)));   // nontemporal-safe
typedef float    nv4f __attribute__((ext_vector_type(4)));

static __device__ __forceinline__ float hlo(unsigned u) {        // low f16 -> f32
    return __half2float(__ushort_as_half((unsigned short)(u & 0xffffu)));
}
static __device__ __forceinline__ float hhi(unsigned u) {        // high f16 -> f32
    return __half2float(__ushort_as_half((unsigned short)(u >> 16)));
}
static __device__ __forceinline__ unsigned pack2h(float a, float b) { // RNE
    return (unsigned)__half_as_ushort(__float2half_rn(a)) |
           ((unsigned)__half_as_ushort(__float2half_rn(b)) << 16);
}
static __device__ __forceinline__ unsigned padd2(unsigned a, unsigned b) {
    __half2 ha = *reinterpret_cast<__half2*>(&a);
    __half2 hb = *reinterpret_cast<__half2*>(&b);
    __half2 hc = __hadd2(ha, hb);                 // v_pk_add_f16
    return *reinterpret_cast<unsigned*>(&hc);
}

// Phase A: pure edge multisplit into K buckets. Per 4096-edge tile: LDS
// histogram -> KMAX scan -> LDS counting-sort -> global reserve ->
// bucket-ordered coalesced write-out.
__global__ void k_binA(const int* __restrict__ src, const int* __restrict__ dst,
                       unsigned* __restrict__ pairs, int* __restrict__ gcursor,
                       int E, int K, int cap) {
    __shared__ unsigned stage[TILEA];        // 16 KB bucket-sorted entries
    __shared__ unsigned short stageB[TILEA]; // 8 KB bucket id per slot
    __shared__ int hist[KMAX];               // counts -> cursors
    __shared__ int lb[KMAX];                 // local exclusive base
    __shared__ int gb[KMAX];                 // global base per bucket
    const int tid = threadIdx.x;        // blockDim = 512
    const long long tb = (long long)blockIdx.x * TILEA;
    const int tcount = (int)min((long long)TILEA, (long long)E - tb);

    hist[tid] = 0;
    __syncthreads();
    int dc[8], sc[8];
    #pragma unroll
    for (int k = 0; k < 8; ++k) {
        int i = tid + k * 512;
        if (i < tcount) {
            dc[k] = dst[tb + i];
            sc[k] = src[tb + i];
            atomicAdd(&hist[dc[k] >> BSHIFT], 1);
        } else {
            dc[k] = -1;
        }
    }
    __syncthreads();
    const int cnt = hist[tid];
    lb[tid] = cnt;
    __syncthreads();
    for (int o = 1; o < KMAX; o <<= 1) {
        int t = (tid >= o) ? lb[tid - o] : 0;
        __syncthreads();
        lb[tid] += t;
        __syncthreads();
    }
    const int excl = lb[tid] - cnt;          // local exclusive base
    __syncthreads();
    lb[tid] = excl;
    gb[tid] = (tid < K && cnt > 0) ? atomicAdd(&gcursor[tid], cnt) : 0;
    hist[tid] = excl;                        // reuse as LDS scatter cursor
    __syncthreads();
    #pragma unroll
    for (int k = 0; k < 8; ++k) {
        if (dc[k] >= 0) {
            int d = dc[k];
            int b = d >> BSHIFT;
            int pos = atomicAdd(&hist[b], 1);
            stage[pos]  = ((unsigned)(d & (NB - 1)) << 23) | (unsigned)sc[k];
            stageB[pos] = (unsigned short)b;
        }
    }
    __syncthreads();
    // bucket-ordered write-out: consecutive j -> consecutive addresses
    for (int j = tid; j < tcount; j += 512) {
        int b = stageB[j];
        pairs[(size_t)b * cap + gb[b] + (j - lb[b])] = stage[j];
    }
}

// Phase B: one block (512 thr) per bucket of 256 nodes. In-kernel gbase
// scan, per-node counts -> LDS scan -> rp/dinv2/rdeg, scatter plain src
// ints to csr via absolute LDS cursors, write csr0 (first 8 slots per
// node, padded with N), then convert own bucket's x (fp32) -> xb (f16)
// AND g0 = f16(dinv * x). Zeroes g0's row N (OOB gather slots).
__global__ void k_binB(const unsigned* __restrict__ pairs, const int* __restrict__ gcursor,
                       int* __restrict__ rp, float* __restrict__ dinv2,
                       float* __restrict__ rdeg, int* __restrict__ csr,
                       int* __restrict__ csr0,
                       const float4* __restrict__ x4,
                       uint4* __restrict__ xb4, uint4* __restrict__ g0,
                       int N, int E, int K, int cap) {
    __shared__ int gsc[KMAX];
    __shared__ int cnt[NB];
    __shared__ int stmp[NB];
    __shared__ int cur[NB];
    __shared__ float sdinv[NB];
    const int b = blockIdx.x;
    const int tid = threadIdx.x;        // blockDim = 512

    if (b == 0 && tid < 8)               // zero row N of g0
        g0[((size_t)N << 3) + tid] = make_uint4(0, 0, 0, 0);

    int gv = (tid < K) ? gcursor[tid] : 0;
    gsc[tid] = gv;
    __syncthreads();
    for (int o = 1; o < KMAX; o <<= 1) {
        int t = (tid >= o) ? gsc[tid - o] : 0;
        __syncthreads();
        gsc[tid] += t;
        __syncthreads();
    }
    const int ecnt = gcursor[b];
    const int base = gsc[b] - ecnt;     // inclusive - own = exclusive
    const unsigned* bp = pairs + (size_t)b * cap;

    if (tid < NB) cnt[tid] = 0;
    __syncthreads();
    for (int i = tid; i < ecnt; i += 512)
        atomicAdd(&cnt[bp[i] >> 23], 1);
    __syncthreads();
    int v = (tid < NB) ? cnt[tid] : 0;
    if (tid < NB) stmp[tid] = v;
    __syncthreads();
    for (int o = 1; o < NB; o <<= 1) {
        int t = (tid >= o && tid < NB) ? stmp[tid - o] : 0;
        __syncthreads();
        if (tid < NB) stmp[tid] += t;
        __syncthreads();
    }
    int node = (b << BSHIFT) + tid;
    if (tid < NB) {
        int abs0 = base + stmp[tid] - v;            // exclusive, absolute
        cur[tid] = abs0;
        float d = fmaxf((float)v, 1.0f);
        sdinv[tid] = rsqrtf(d);
        if (node < N) {
            rp[node] = abs0;
            dinv2[node] = 1.0f / d;
            rdeg[node]  = sqrtf(d);
        }
    }
    if (b == K - 1 && tid == 0) rp[N] = E;
    __syncthreads();
    for (int i = tid; i < ecnt; i += 512) {
        unsigned p = bp[i];
        int pos = atomicAdd(&cur[p >> 23], 1);      // absolute csr index
        csr[pos] = (int)(p & 0x7FFFFFu);
    }
    __syncthreads();                                 // csr of this bucket done
    // csr0: first 8 slots per node, padded with N (zero row)
    if (tid < NB && node < N) {
        int abs0 = base + stmp[tid] - v;
        int4 q0, q1;
        q0.x = (0 < v) ? csr[abs0 + 0] : N;
        q0.y = (1 < v) ? csr[abs0 + 1] : N;
        q0.z = (2 < v) ? csr[abs0 + 2] : N;
        q0.w = (3 < v) ? csr[abs0 + 3] : N;
        q1.x = (4 < v) ? csr[abs0 + 4] : N;
        q1.y = (5 < v) ? csr[abs0 + 5] : N;
        q1.z = (6 < v) ? csr[abs0 + 6] : N;
        q1.w = (7 < v) ? csr[abs0 + 7] : N;
        *(int4*)(csr0 + ((size_t)node << 3))     = q0;
        *(int4*)(csr0 + ((size_t)node << 3) + 4) = q1;
    }
    // fused convert for this bucket's nodes: x (fp32) -> xb, g0 = dinv*x
    const int nbase = b << BSHIFT;
    const int qmax = min(NB, N - nbase) << 3;       // 8 uint4 per node
    uint4* g0p = g0 + ((size_t)nbase << 3);
    for (int q = tid; q < qmax; q += 512) {
        int gq = ((nbase + (q >> 3)) << 3) + (q & 7);   // global uint4 idx
        float4 a = x4[2 * gq];
        float4 bb = x4[2 * gq + 1];
        uint4 xo;
        xo.x = pack2h(a.x, a.y);
        xo.y = pack2h(a.z, a.w);
        xo.z = pack2h(bb.x, bb.y);
        xo.w = pack2h(bb.z, bb.w);
        xb4[gq] = xo;
        float di = sdinv[q >> 3];
        uint4 go;
        go.x = pack2h(di * a.x, di * a.y);
        go.y = pack2h(di * a.z, di * a.w);
        go.z = pack2h(di * bb.x, di * bb.y);
        go.w = pack2h(di * bb.z, di * bb.w);
        g0p[q] = go;
    }
}

// TWO nodes per wave, f16 feature tables (128B rows), depth-2 software
// pipeline. Lane l: half = l>>5, r = (l>>3)&3, c = l&7.
// First-iteration row indices come from csr0 (no rp dependency); epilogue
// node-addressed loads are hoisted to the prologue under the r==0 mask.
// Packed v_pk_add_f16 accumulate; OOB slots gather zero row n.
// !LAST epilogue: gout[d] = f16(gin[d] - dinv2[d]*acc)  (+ zero row N)
//  LAST epilogue: h[d] = t0*xb[d] + rdeg[d]*(t1*g1+t2*g2+t3*gin+t4*g4),
//                 g4 = gin[d] - dinv2[d]*acc computed in-register.
template <bool LAST>
__global__ void k_gather(const int* __restrict__ rp, const int* __restrict__ csr,
                         const int* __restrict__ csr0,
                         const unsigned short* __restrict__ gin,
                         const float* __restrict__ dinv2,
                         unsigned short* __restrict__ gout,
                         const unsigned short* __restrict__ xb,
                         const unsigned short* __restrict__ g1t,
                         const unsigned short* __restrict__ g2t,
                         const float* __restrict__ rdeg,
                         float* __restrict__ h, int n,
                         float t0, float t1, float t2, float t3, float t4) {
    if (!LAST && blockIdx.x == 0 && threadIdx.x < 8)   // zero row N of gout
        *(((uint4*)(gout + ((size_t)n << 6))) + threadIdx.x) = make_uint4(0, 0, 0, 0);

    int wid = (blockIdx.x * blockDim.x + threadIdx.x) >> 6;
    int lane = threadIdx.x & 63;
    int half = lane >> 5;
    int r = (lane >> 3) & 3;
    int c = lane & 7;
    int node = wid * 2 + half;
    if (wid * 2 >= n) return;
    bool valid = node < n;

    // first-iteration row indices: independent of rp (breaks the chain)
    int s1 = n, s2 = n;
    if (valid) {
        s1 = csr0[((size_t)node << 3) + r];
        s2 = csr0[((size_t)node << 3) + r + 4];
    }
    int beg = valid ? rp[node] : 0;
    int end = valid ? rp[node + 1] : 0;

    // hoisted epilogue loads (node-addressed, exec-masked to 16 lanes)
    const bool ep = (r == 0) && valid;
    size_t off = ((size_t)node << 6) + (c << 3);
    uint4 rr = make_uint4(0, 0, 0, 0);
    float d2 = 0.f, rd = 0.f;
    nv4u xv = {0u, 0u, 0u, 0u}, aa = {0u, 0u, 0u, 0u}, bb = {0u, 0u, 0u, 0u};
    if (ep) {
        rr = *(const uint4*)(gin + off);
        d2 = dinv2[node];
        if (LAST) {
            xv = __builtin_nontemporal_load((const nv4u*)(xb + off));
            aa = __builtin_nontemporal_load((const nv4u*)(g1t + off));
            bb = __builtin_nontemporal_load((const nv4u*)(g2t + off));
            rd = rdeg[node];
        }
    }

    int len = end - beg;
    int olen = __shfl_xor(len, 32, 64);
    int mlen = (len > olen) ? len : olen;   // pair max -> uniform trip count

    unsigned acc[4] = {0u, 0u, 0u, 0u};     // packed f16 pairs

    // pipeline state: current rows (in flight), next row indices
    uint4 rc1 = *(const uint4*)(gin + ((size_t)s1 << 6) + (c << 3));
    uint4 rc2 = *(const uint4*)(gin + ((size_t)s2 << 6) + (c << 3));
    int sn1 = n, sn2 = n;
    {
        int j1b = beg + 8 + r, j2b = j1b + 4;
        bool vb = 8 < mlen;
        bool b1 = vb && (j1b < end), b2 = vb && (j2b < end);
        sn1 = csr[b1 ? j1b : 0]; sn1 = b1 ? sn1 : n;
        sn2 = csr[b2 ? j2b : 0]; sn2 = b2 ? sn2 : n;
    }
    for (int i = 0; i < mlen; i += 8) {
        // issue NEXT iteration's rows (independent of rc1/rc2 wait)
        uint4 rn1 = *(const uint4*)(gin + ((size_t)sn1 << 6) + (c << 3));
        uint4 rn2 = *(const uint4*)(gin + ((size_t)sn2 << 6) + (c << 3));
        // prefetch csr two iterations ahead
        int j1n = beg + i + 16 + r, j2n = j1n + 4;
        bool vn = (i + 16) < mlen;
        bool t1c = vn && (j1n < end), t2c = vn && (j2n < end);
        int st1 = csr[t1c ? j1n : 0]; st1 = t1c ? st1 : n;
        int st2 = csr[t2c ? j2n : 0]; st2 = t2c ? st2 : n;
        // accumulate CURRENT rows (packed f16)
        acc[0] = padd2(acc[0], rc1.x); acc[1] = padd2(acc[1], rc1.y);
        acc[2] = padd2(acc[2], rc1.z); acc[3] = padd2(acc[3], rc1.w);
        acc[0] = padd2(acc[0], rc2.x); acc[1] = padd2(acc[1], rc2.y);
        acc[2] = padd2(acc[2], rc2.z); acc[3] = padd2(acc[3], rc2.w);
        // rotate pipeline
        rc1 = rn1; rc2 = rn2;
        sn1 = st1; sn2 = st2;
    }
    #pragma unroll
    for (int m = 8; m <= 16; m <<= 1) {
        #pragma unroll
        for (int i = 0; i < 4; ++i)
            acc[i] = padd2(acc[i], __shfl_xor(acc[i], m, 64));
    }

    if (ep) {                                // lanes 0..7 and 32..39
        float v[8];
        v[0] = hlo(rr.x) - d2 * hlo(acc[0]); v[1] = hhi(rr.x) - d2 * hhi(acc[0]);
        v[2] = hlo(rr.y) - d2 * hlo(acc[1]); v[3] = hhi(rr.y) - d2 * hhi(acc[1]);
        v[4] = hlo(rr.z) - d2 * hlo(acc[2]); v[5] = hhi(rr.z) - d2 * hhi(acc[2]);
        v[6] = hlo(rr.w) - d2 * hlo(acc[3]); v[7] = hhi(rr.w) - d2 * hhi(acc[3]);
        if (!LAST) {
            nv4u o;
            o.x = pack2h(v[0], v[1]);
            o.y = pack2h(v[2], v[3]);
            o.z = pack2h(v[4], v[5]);
            o.w = pack2h(v[6], v[7]);
            __builtin_nontemporal_store(o, (nv4u*)(gout + off));
        } else {
            float s1f = rd * t1, s2f = rd * t2, s3f = rd * t3, s4f = rd * t4;
            nv4f h0, h1;
            h0.x = t0 * hlo(xv.x) + s1f * hlo(aa.x) + s2f * hlo(bb.x) + s3f * hlo(rr.x) + s4f * v[0];
            h0.y = t0 * hhi(xv.x) + s1f * hhi(aa.x) + s2f * hhi(bb.x) + s3f * hhi(rr.x) + s4f * v[1];
            h0.z = t0 * hlo(xv.y) + s1f * hlo(aa.y) + s2f * hlo(bb.y) + s3f * hlo(rr.y) + s4f * v[2];
            h0.w = t0 * hhi(xv.y) + s1f * hhi(aa.y) + s2f * hhi(bb.y) + s3f * hhi(rr.y) + s4f * v[3];
            h1.x = t0 * hlo(xv.z) + s1f * hlo(aa.z) + s2f * hlo(bb.z) + s3f * hlo(rr.z) + s4f * v[4];
            h1.y = t0 * hhi(xv.z) + s1f * hhi(aa.z) + s2f * hhi(bb.z) + s3f * hhi(rr.z) + s4f * v[5];
            h1.z = t0 * hlo(xv.w) + s1f * hlo(aa.w) + s2f * hlo(bb.w) + s3f * hlo(rr.w) + s4f * v[6];
            h1.w = t0 * hhi(xv.w) + s1f * hhi(aa.w) + s2f * hhi(bb.w) + s3f * hhi(rr.w) + s4f * v[7];
            __builtin_nontemporal_store(h0, (nv4f*)(h + off));
            __builtin_nontemporal_store(h1, (nv4f*)(h + off + 4));
        }
    }
}

extern "C" void kernel_launch(void* const* d_in, const int* in_sizes, int n_in,
                              void* d_out, int out_size, void* d_ws, size_t ws_size,
                              hipStream_t stream) {
    const float* x  = (const float*)d_in[0];
    const int*   ei = (const int*)d_in[1];   // edge_index [2, E] row-major
    const int N = in_sizes[0] / kF;
    const int E = in_sizes[1] / 2;
    const int* src = ei;
    const int* dst = ei + E;
    float* h = (float*)d_out;

    const int K = (N + NB - 1) >> BSHIFT;         // 391 buckets (K <= KMAX)
    const int cap = 2 * ((E + K - 1) / K);        // per-bucket capacity

    // workspace (~76 MB): gcursor | rp | dinv2 | rdeg | csr | csr0 | xb |
    // g0 | g1 (aliases pairs; pairs dead after binB) | g2 | g3
    char* ws = (char*)d_ws;
    size_t off = 0;
    auto carve = [&](size_t bytes) {
        void* p = ws + off;
        off = (off + bytes + 511) & ~(size_t)511;
        return p;
    };
    size_t gbytes = (size_t)(N + 1) * kF * 2;
    int*            gcursor = (int*)carve((size_t)KMAX * 4);
    int*            rp      = (int*)carve((size_t)(N + 1) * 4);
    float*          dinv2   = (float*)carve((size_t)N * 4);
    float*          rdeg    = (float*)carve((size_t)N * 4);
    int*            csr     = (int*)carve((size_t)E * 4);
    int*            csr0    = (int*)carve((size_t)N * 8 * 4);
    unsigned short* xb      = (unsigned short*)carve((size_t)N * kF * 2);
    unsigned short* g0      = (unsigned short*)carve(gbytes);
    size_t pbytes = (size_t)K * cap * 4;
    unsigned short* g1      = (unsigned short*)carve(gbytes > pbytes ? gbytes : pbytes);
    unsigned short* g2      = (unsigned short*)carve(gbytes);
    unsigned short* g3      = (unsigned short*)carve(gbytes);
    unsigned*       pairs   = (unsigned*)g1;       // alias (dead after binB)

    const float theta[5] = {0.6f, -0.4f, 0.3f, -0.2f, 0.1f};

    // ---- CSR build (multisplit); binB also does x->xb and g0 ----
    hipMemsetAsync(gcursor, 0, (size_t)KMAX * 4, stream);
    k_binA<<<(E + TILEA - 1) / TILEA, 512, 0, stream>>>(src, dst, pairs, gcursor,
                                                        E, K, cap);
    k_binB<<<K, 512, 0, stream>>>(pairs, gcursor, rp, dinv2, rdeg, csr, csr0,
                                  (const float4*)x, (uint4*)xb, (uint4*)g0,
                                  N, E, K, cap);

    // ---- 4 gather passes; pass 4 fuses the h-combine epilogue ----
    const int nwaves = (N + 1) / 2;                // 2 nodes per wave
    const int gblocks = (nwaves + 3) / 4;          // 4 waves per 256-thread block
    k_gather<false><<<gblocks, 256, 0, stream>>>(rp, csr, csr0, g0, dinv2, g1,
                                                 nullptr, nullptr, nullptr, nullptr,
                                                 nullptr, N, 0, 0, 0, 0, 0);
    k_gather<false><<<gblocks, 256, 0, stream>>>(rp, csr, csr0, g1, dinv2, g2,
                                                 nullptr, nullptr, nullptr, nullptr,
                                                 nullptr, N, 0, 0, 0, 0, 0);
    k_gather<false><<<gblocks, 256, 0, stream>>>(rp, csr, csr0, g2, dinv2, g3,
                                                 nullptr, nullptr, nullptr, nullptr,
                                                 nullptr, N, 0, 0, 0, 0, 0);
    k_gather<true><<<gblocks, 256, 0, stream>>>(rp, csr, csr0, g3, dinv2, nullptr,
                                                xb, g1, g2, rdeg, h, N,
                                                theta[0], theta[1], theta[2],
                                                theta[3], theta[4]);
}